// Round 6
// baseline (36.758 us; speedup 1.0000x reference)
//
#include <hip/hip_runtime.h>
#include <math.h>

#define EPS 1e-6f
#define LOG2E 1.4426950408889634f

constexpr int TB  = 256;   // threads/block (4 waves)
constexpr int TD  = 256;   // dense tile dim (1 i-row/thread, TD j's per tile)
constexpr int EPT = 8;     // edges per thread

__device__ __forceinline__ float readlane_f(float v, int l) {
    return __int_as_float(__builtin_amdgcn_readlane(__float_as_int(v), l));
}

// Fused kernel (R4 structure: NO cross-block sync — R5's threadfence/atomic
// variant regressed 10us). Blocks [0, nd): dense triangular tile-pairs.
// Blocks [nd, nd+ne): edge chunks. part[] homogeneous, pre-weighted.
//
// Dense j-tile broadcast: REGISTERS + v_readlane instead of LDS. The LDS pipe
// is CU-shared (12 cyc/ds_read_b128 x ~13 waves/CU = ~16us demand — the real
// R4 bottleneck); readlane runs on the per-SIMD VALU pipe. Per wave-iter:
// 3 readlane + 5 VALU (16 cyc) || 2 trans (16 cyc) — balanced.
__global__ void __launch_bounds__(TB) k_fused(
    const float2* __restrict__ Z, const float* __restrict__ gamma,
    const int* __restrict__ ei, const int* __restrict__ ej,
    float* __restrict__ part, int n, int nb, int nd, int e)
{
    __shared__ float wsum[TB / 64];
    const int bx = blockIdx.x;
    const int lane = threadIdx.x & 63;
    float acc = 0.f;
    float blockw = 1.f;

    if (bx < nd) {
        // ---- dense role: decode triangular index -> (a,b), b >= a ----
        auto before = [nb](int x) { return x * nb - (x * (x - 1)) / 2; };
        int a = (int)(((2 * nb + 1) -
                       sqrtf((float)((2 * nb + 1) * (2 * nb + 1) - 8 * bx))) * 0.5f);
        if (a < 0) a = 0;
        if (a > nb - 1) a = nb - 1;
        while (before(a + 1) <= bx) ++a;
        while (before(a) > bx) --a;
        const int b = a + (bx - before(a));

        const int j0 = b * TD;

        // j-tile into registers: lane holds j = j0 + 64*g + lane, g=0..3.
        // (loaded by ALL threads — masked-off i-rows still serve as data
        // holders; v_readlane ignores EXEC.)
        float rx[4], ry[4], rg[4];
        #pragma unroll
        for (int g = 0; g < 4; ++g) {
            int j  = j0 + g * 64 + lane;
            int jc = j < n ? j : n - 1;
            float2 z = Z[jc];
            rx[g] = z.x * LOG2E;
            ry[g] = z.y * LOG2E;
            rg[g] = (j < n) ? __expf(gamma[jc]) : 0.f;  // tail j's contribute 0
        }

        const int i = a * TD + threadIdx.x;
        if (i < n) {
            float2 zi = Z[i];
            const float ax = (zi.x + EPS) * LOG2E;
            const float ay = (zi.y + EPS) * LOG2E;
            #pragma unroll
            for (int g = 0; g < 4; ++g) {
                #pragma unroll 16
                for (int l = 0; l < 64; ++l) {
                    float sx = readlane_f(rx[g], l);
                    float sy = readlane_f(ry[g], l);
                    float sg = readlane_f(rg[g], l);
                    float dx = ax - sx;             // difference form: d2 >= 0
                    float dy = ay - sy;
                    float r  = __builtin_amdgcn_sqrtf(fmaf(dx, dx, dy * dy));
                    acc = fmaf(sg, __builtin_amdgcn_exp2f(-r), acc);
                }
            }
            float egi = __expf(gamma[i]);
            if (a == b) acc -= egi * 0.9999985858f;  // exp(-sqrt(2)*EPS)
            acc *= egi;
        }
        blockw = (a == b) ? -0.5f : -1.0f;
    } else {
        // ---- edge role ----
        const int c = bx - nd;
        const long base = ((long)c * TB + threadIdx.x) * EPT;
        if (base + EPT <= e) {
            int4 ia0 = *(const int4*)(ei + base);
            int4 ia1 = *(const int4*)(ei + base + 4);
            int4 ja0 = *(const int4*)(ej + base);
            int4 ja1 = *(const int4*)(ej + base + 4);
            const int as[EPT] = {ia0.x, ia0.y, ia0.z, ia0.w,
                                 ia1.x, ia1.y, ia1.z, ia1.w};
            const int bs[EPT] = {ja0.x, ja0.y, ja0.z, ja0.w,
                                 ja1.x, ja1.y, ja1.z, ja1.w};
            #pragma unroll
            for (int k = 0; k < EPT; ++k) {
                float2 za = Z[as[k]], zb = Z[bs[k]];
                float dx = za.x - zb.x + EPS;
                float dy = za.y - zb.y + EPS;
                float r = __builtin_amdgcn_sqrtf(fmaf(dx, dx, dy * dy));
                acc += gamma[as[k]] + gamma[bs[k]] - r;
            }
        } else {
            for (int k = 0; k < EPT; ++k) {
                long idx = base + k;
                if (idx < e) {
                    int ai = ei[idx], bi = ej[idx];
                    float2 za = Z[ai], zb = Z[bi];
                    float dx = za.x - zb.x + EPS;
                    float dy = za.y - zb.y + EPS;
                    float r = __builtin_amdgcn_sqrtf(fmaf(dx, dx, dy * dy));
                    acc += gamma[ai] + gamma[bi] - r;
                }
            }
        }
        blockw = 1.f;
    }

    // fixed-order deterministic block reduction
    for (int off = 32; off > 0; off >>= 1) acc += __shfl_down(acc, off, 64);
    const int w = threadIdx.x >> 6;
    if (lane == 0) wsum[w] = acc;
    __syncthreads();
    if (threadIdx.x == 0) {
        float s = 0.f;
        #pragma unroll
        for (int k = 0; k < TB / 64; ++k) s += wsum[k];
        part[bx] = blockw * s;
    }
}

// Final: out[0] = sum(part[0..np)) in fp64, fixed tree order.
__global__ void __launch_bounds__(256) k_final(
    const float* __restrict__ part, int np, float* __restrict__ out)
{
    double sd = 0.0;
    for (int t = threadIdx.x; t < np; t += 256) sd += (double)part[t];
    __shared__ double sh[256];
    sh[threadIdx.x] = sd;
    __syncthreads();
    for (int s = 128; s > 0; s >>= 1) {
        if (threadIdx.x < s) sh[threadIdx.x] += sh[threadIdx.x + s];
        __syncthreads();
    }
    if (threadIdx.x == 0) out[0] = (float)sh[0];
}

extern "C" void kernel_launch(void* const* d_in, const int* in_sizes, int n_in,
                              void* d_out, int out_size, void* d_ws, size_t ws_size,
                              hipStream_t stream)
{
    const float2* Z     = (const float2*)d_in[0];
    const float*  gamma = (const float*)d_in[1];
    const int*    ei    = (const int*)d_in[2];
    const int*    ej    = (const int*)d_in[3];
    const int n = in_sizes[1];
    const int e = in_sizes[2];
    float* out = (float*)d_out;

    const int nb = (n + TD - 1) / TD;
    const int nd = nb * (nb + 1) / 2;
    const int ne = (e + TB * EPT - 1) / (TB * EPT);
    const int np = nd + ne;

    float* part = (float*)d_ws;

    hipLaunchKernelGGL(k_fused, dim3(np), dim3(TB), 0, stream,
                       Z, gamma, ei, ej, part, n, nb, nd, e);
    hipLaunchKernelGGL(k_final, dim3(1), dim3(256), 0, stream,
                       part, np, out);
}

// Round 7
// 26.083 us; speedup vs baseline: 1.4092x; 1.4092x over previous
//
#include <hip/hip_runtime.h>
#include <math.h>

#define EPS 1e-6f
#define LOG2E 1.4426950408889634f

constexpr int TB  = 128;   // threads/block (2 waves)
constexpr int TD  = 128;   // dense tile dim (1 i-row/thread, TD j's in LDS)
constexpr int EPT = 16;    // edges per thread

// R4 structure (best: 25.9us) with 128^2 dense tiles for trans-pipe
// saturation: nd=3160 blocks (12.3/CU, 6.2 waves/SIMD) vs 256^2's 820
// (3.2/CU, 25% CU-quantization tail). Per-pair cost unchanged:
// 1 broadcast ds_read_b128 + 5 full-rate VALU + 2 trans (sqrt, exp2).
// R5 lesson: no cross-block fences/atomics (L2-writeback cost ~10us).
// R6 lesson: readlane broadcast is SLOWER than LDS (extra VALU issue).
__global__ void __launch_bounds__(TB) k_fused(
    const float2* __restrict__ Z, const float* __restrict__ gamma,
    const int* __restrict__ ei, const int* __restrict__ ej,
    float* __restrict__ part, int n, int nb, int nd, int e)
{
    __shared__ float4 sj[TD];
    __shared__ float wsum[TB / 64];
    const int bx = blockIdx.x;
    float acc = 0.f;
    float blockw = 1.f;

    if (bx < nd) {
        // ---- dense role: decode triangular index -> (a,b), b >= a ----
        auto before = [nb](int x) { return x * nb - (x * (x - 1)) / 2; };
        int a = (int)(((2 * nb + 1) -
                       sqrtf((float)((2 * nb + 1) * (2 * nb + 1) - 8 * bx))) * 0.5f);
        if (a < 0) a = 0;
        if (a > nb - 1) a = nb - 1;
        while (before(a + 1) <= bx) ++a;
        while (before(a) > bx) --a;
        const int b = a + (bx - before(a));

        const int j0 = b * TD;
        const int jn = min(TD, n - j0);

        if (threadIdx.x < jn) {
            const int j = j0 + threadIdx.x;
            float2 z = Z[j];
            sj[threadIdx.x] = make_float4(z.x * LOG2E, z.y * LOG2E,
                                          __expf(gamma[j]), 0.f);
        }
        __syncthreads();

        const int i = a * TD + threadIdx.x;
        if (i < n) {
            float2 zi = Z[i];
            const float ax = (zi.x + EPS) * LOG2E;
            const float ay = (zi.y + EPS) * LOG2E;
            #pragma unroll 8
            for (int k = 0; k < jn; ++k) {
                float4 s = sj[k];
                float dx = ax - s.x;              // difference form: d2 >= 0
                float dy = ay - s.y;
                float r = __builtin_amdgcn_sqrtf(fmaf(dx, dx, dy * dy));
                acc = fmaf(s.z, __builtin_amdgcn_exp2f(-r), acc);
            }
            float egi = __expf(gamma[i]);
            if (a == b) acc -= egi * 0.9999985858f;  // exp(-sqrt(2)*EPS)
            acc *= egi;
        }
        blockw = (a == b) ? -0.5f : -1.0f;
    } else {
        // ---- edge role ----
        const int c = bx - nd;
        const long base = ((long)c * TB + threadIdx.x) * EPT;
        if (base + EPT <= e) {
            #pragma unroll
            for (int q = 0; q < EPT / 4; ++q) {
                int4 ia = *(const int4*)(ei + base + 4 * q);
                int4 ja = *(const int4*)(ej + base + 4 * q);
                const int as[4] = {ia.x, ia.y, ia.z, ia.w};
                const int bs[4] = {ja.x, ja.y, ja.z, ja.w};
                #pragma unroll
                for (int k = 0; k < 4; ++k) {
                    float2 za = Z[as[k]], zb = Z[bs[k]];
                    float dx = za.x - zb.x + EPS;
                    float dy = za.y - zb.y + EPS;
                    float r = __builtin_amdgcn_sqrtf(fmaf(dx, dx, dy * dy));
                    acc += gamma[as[k]] + gamma[bs[k]] - r;
                }
            }
        } else {
            for (int k = 0; k < EPT; ++k) {
                long idx = base + k;
                if (idx < e) {
                    int ai = ei[idx], bi = ej[idx];
                    float2 za = Z[ai], zb = Z[bi];
                    float dx = za.x - zb.x + EPS;
                    float dy = za.y - zb.y + EPS;
                    float r = __builtin_amdgcn_sqrtf(fmaf(dx, dx, dy * dy));
                    acc += gamma[ai] + gamma[bi] - r;
                }
            }
        }
        blockw = 1.f;
    }

    // fixed-order deterministic block reduction
    for (int off = 32; off > 0; off >>= 1) acc += __shfl_down(acc, off, 64);
    const int lane = threadIdx.x & 63, w = threadIdx.x >> 6;
    if (lane == 0) wsum[w] = acc;
    __syncthreads();
    if (threadIdx.x == 0) {
        float s = 0.f;
        #pragma unroll
        for (int k = 0; k < TB / 64; ++k) s += wsum[k];
        part[bx] = blockw * s;
    }
}

// Final: out[0] = sum(part[0..np)) in fp64, fixed tree order.
__global__ void __launch_bounds__(256) k_final(
    const float* __restrict__ part, int np, float* __restrict__ out)
{
    double sd = 0.0;
    for (int t = threadIdx.x; t < np; t += 256) sd += (double)part[t];
    __shared__ double sh[256];
    sh[threadIdx.x] = sd;
    __syncthreads();
    for (int s = 128; s > 0; s >>= 1) {
        if (threadIdx.x < s) sh[threadIdx.x] += sh[threadIdx.x + s];
        __syncthreads();
    }
    if (threadIdx.x == 0) out[0] = (float)sh[0];
}

extern "C" void kernel_launch(void* const* d_in, const int* in_sizes, int n_in,
                              void* d_out, int out_size, void* d_ws, size_t ws_size,
                              hipStream_t stream)
{
    const float2* Z     = (const float2*)d_in[0];
    const float*  gamma = (const float*)d_in[1];
    const int*    ei    = (const int*)d_in[2];
    const int*    ej    = (const int*)d_in[3];
    const int n = in_sizes[1];
    const int e = in_sizes[2];
    float* out = (float*)d_out;

    const int nb = (n + TD - 1) / TD;
    const int nd = nb * (nb + 1) / 2;
    const int ne = (e + TB * EPT - 1) / (TB * EPT);
    const int np = nd + ne;

    float* part = (float*)d_ws;

    hipLaunchKernelGGL(k_fused, dim3(np), dim3(TB), 0, stream,
                       Z, gamma, ei, ej, part, n, nb, nd, e);
    hipLaunchKernelGGL(k_final, dim3(1), dim3(256), 0, stream,
                       part, np, out);
}

// Round 8
// 24.212 us; speedup vs baseline: 1.5182x; 1.0773x over previous
//
#include <hip/hip_runtime.h>
#include <math.h>

#define EPS 1e-6f
#define LOG2E 1.4426950408889634f
// Schraudolph exp2 bias: (127 + c)*2^23 with c = -0.0566 chosen for ZERO-MEAN
// relative error over uniform mantissa fraction (error range ~[-5.7%, +2.0%]).
#define SCHRAUD_K 1064878421.0f

constexpr int TB  = 256;   // threads/block (4 waves)
constexpr int TD  = 256;   // dense tile dim (1 i-row/thread, TD j's in LDS)
constexpr int EPT = 8;     // edges per thread

// exp2(-rp) ~ Schraudolph: 2 full-rate VALU ops (fma + cvt) vs 8-cyc trans.
__device__ __forceinline__ float fast_exp2_neg(float rp) {
    return __int_as_float((int)fmaf(rp, -8388608.0f, SCHRAUD_K));
}

// Blocks [0, ne): edge chunks (FIRST: their L2-gather latency hides under the
// dense compute that follows). Blocks [ne, ne+nd): dense triangular tiles.
// part[] homogeneous pre-weighted: answer = sum(part).
// Dense per-pair: ds_read share + {sub,sub,mul,fma} + v_sqrt(trans) +
// {fma,cvt} schraudolph + fma(acc) = ~24 issue-cyc/64 pairs vs 32 exact.
// LDS is pair-interleaved (x0,x1,y0,y1)/(w0,w1) to invite v_pk_* codegen.
__global__ void __launch_bounds__(TB) k_fused(
    const float2* __restrict__ Z, const float* __restrict__ gamma,
    const int* __restrict__ ei, const int* __restrict__ ej,
    float* __restrict__ part, int n, int nb, int ne, int e)
{
    __shared__ float4 sXY[TD / 2];   // (x_2k, x_2k+1, y_2k, y_2k+1) * LOG2E
    __shared__ float2 sW[TD / 2];    // (exp(g_2k), exp(g_2k+1))
    __shared__ float wsum[TB / 64];
    const int bx = blockIdx.x;
    float acc = 0.f;
    float blockw = 1.f;

    if (bx >= ne) {
        // ---- dense role: decode triangular index -> (a,b), b >= a ----
        const int t = bx - ne;
        auto before = [nb](int x) { return x * nb - (x * (x - 1)) / 2; };
        int a = (int)(((2 * nb + 1) -
                       sqrtf((float)((2 * nb + 1) * (2 * nb + 1) - 8 * t))) * 0.5f);
        if (a < 0) a = 0;
        if (a > nb - 1) a = nb - 1;
        while (before(a + 1) <= t) ++a;
        while (before(a) > t) --a;
        const int b = a + (t - before(a));

        const int j0 = b * TD;

        // stage TD j's as pairs; threads [0, TD/2) each own one pair
        if (threadIdx.x < TD / 2) {
            const int k  = threadIdx.x;
            const int j1 = j0 + 2 * k, j2 = j1 + 1;
            float4 xy;
            float2 w;
            if (j2 < n) {                      // fast in-bounds pair
                float4 zz = *(const float4*)(&Z[j1]);   // (x1,y1,x2,y2)
                float2 gg = *(const float2*)(&gamma[j1]);
                xy = make_float4(zz.x * LOG2E, zz.z * LOG2E,
                                 zz.y * LOG2E, zz.w * LOG2E);
                w  = make_float2(__expf(gg.x), __expf(gg.y));
            } else {                           // clamped tail (last tile only)
                int c1 = j1 < n ? j1 : n - 1;
                int c2 = j2 < n ? j2 : n - 1;
                float2 z1 = Z[c1], z2 = Z[c2];
                xy = make_float4(z1.x * LOG2E, z2.x * LOG2E,
                                 z1.y * LOG2E, z2.y * LOG2E);
                w  = make_float2(j1 < n ? __expf(gamma[c1]) : 0.f,
                                 j2 < n ? __expf(gamma[c2]) : 0.f);
            }
            sXY[k] = xy;
            sW[k]  = w;
        }
        __syncthreads();

        const int i = a * TD + threadIdx.x;
        if (i < n) {
            float2 zi = Z[i];
            const float ax = (zi.x + EPS) * LOG2E;
            const float ay = (zi.y + EPS) * LOG2E;
            float acc0 = 0.f, acc1 = 0.f;
            #pragma unroll 8
            for (int k = 0; k < TD / 2; ++k) {
                float4 p = sXY[k];
                float2 w = sW[k];
                float dx0 = ax - p.x, dx1 = ax - p.y;   // pairable (pk_sub)
                float dy0 = ay - p.z, dy1 = ay - p.w;
                float d20 = fmaf(dx0, dx0, dy0 * dy0);  // difference form >= 0
                float d21 = fmaf(dx1, dx1, dy1 * dy1);
                float r0 = __builtin_amdgcn_sqrtf(d20);
                float r1 = __builtin_amdgcn_sqrtf(d21);
                acc0 = fmaf(w.x, fast_exp2_neg(r0), acc0);
                acc1 = fmaf(w.y, fast_exp2_neg(r1), acc1);
            }
            acc = acc0 + acc1;
            float egi = __expf(gamma[i]);
            if (a == b) {
                // subtract diag through the SAME approximant so it cancels
                acc -= egi * fast_exp2_neg(1.41421356e-6f * LOG2E);
            }
            acc *= egi;
        }
        blockw = (a == b) ? -0.5f : -1.0f;
    } else {
        // ---- edge role (exact trans; latency-bound, not issue-bound) ----
        const long base = ((long)bx * TB + threadIdx.x) * EPT;
        if (base + EPT <= e) {
            int4 ia0 = *(const int4*)(ei + base);
            int4 ia1 = *(const int4*)(ei + base + 4);
            int4 ja0 = *(const int4*)(ej + base);
            int4 ja1 = *(const int4*)(ej + base + 4);
            const int as[EPT] = {ia0.x, ia0.y, ia0.z, ia0.w,
                                 ia1.x, ia1.y, ia1.z, ia1.w};
            const int bs[EPT] = {ja0.x, ja0.y, ja0.z, ja0.w,
                                 ja1.x, ja1.y, ja1.z, ja1.w};
            #pragma unroll
            for (int k = 0; k < EPT; ++k) {
                float2 za = Z[as[k]], zb = Z[bs[k]];
                float dx = za.x - zb.x + EPS;
                float dy = za.y - zb.y + EPS;
                float r = __builtin_amdgcn_sqrtf(fmaf(dx, dx, dy * dy));
                acc += gamma[as[k]] + gamma[bs[k]] - r;
            }
        } else {
            for (int k = 0; k < EPT; ++k) {
                long idx = base + k;
                if (idx < e) {
                    int ai = ei[idx], bi = ej[idx];
                    float2 za = Z[ai], zb = Z[bi];
                    float dx = za.x - zb.x + EPS;
                    float dy = za.y - zb.y + EPS;
                    float r = __builtin_amdgcn_sqrtf(fmaf(dx, dx, dy * dy));
                    acc += gamma[ai] + gamma[bi] - r;
                }
            }
        }
        blockw = 1.f;
    }

    // fixed-order deterministic block reduction
    for (int off = 32; off > 0; off >>= 1) acc += __shfl_down(acc, off, 64);
    const int lane = threadIdx.x & 63, w = threadIdx.x >> 6;
    if (lane == 0) wsum[w] = acc;
    __syncthreads();
    if (threadIdx.x == 0) {
        float s = 0.f;
        #pragma unroll
        for (int k = 0; k < TB / 64; ++k) s += wsum[k];
        part[bx] = blockw * s;
    }
}

// Final: out[0] = sum(part[0..np)) in fp64, fixed tree order.
__global__ void __launch_bounds__(256) k_final(
    const float* __restrict__ part, int np, float* __restrict__ out)
{
    double sd = 0.0;
    for (int t = threadIdx.x; t < np; t += 256) sd += (double)part[t];
    __shared__ double sh[256];
    sh[threadIdx.x] = sd;
    __syncthreads();
    for (int s = 128; s > 0; s >>= 1) {
        if (threadIdx.x < s) sh[threadIdx.x] += sh[threadIdx.x + s];
        __syncthreads();
    }
    if (threadIdx.x == 0) out[0] = (float)sh[0];
}

extern "C" void kernel_launch(void* const* d_in, const int* in_sizes, int n_in,
                              void* d_out, int out_size, void* d_ws, size_t ws_size,
                              hipStream_t stream)
{
    const float2* Z     = (const float2*)d_in[0];
    const float*  gamma = (const float*)d_in[1];
    const int*    ei    = (const int*)d_in[2];
    const int*    ej    = (const int*)d_in[3];
    const int n = in_sizes[1];
    const int e = in_sizes[2];
    float* out = (float*)d_out;

    const int nb = (n + TD - 1) / TD;
    const int nd = nb * (nb + 1) / 2;
    const int ne = (e + TB * EPT - 1) / (TB * EPT);
    const int np = ne + nd;

    float* part = (float*)d_ws;

    hipLaunchKernelGGL(k_fused, dim3(np), dim3(TB), 0, stream,
                       Z, gamma, ei, ej, part, n, nb, ne, e);
    hipLaunchKernelGGL(k_final, dim3(1), dim3(256), 0, stream,
                       part, np, out);
}